// Round 8
// baseline (5394.788 us; speedup 1.0000x reference)
//
#include <hip/hip_runtime.h>
#include <hip/hip_cooperative_groups.h>
#include <math.h>

namespace cg = cooperative_groups;

typedef unsigned short u16;
typedef __attribute__((ext_vector_type(8))) short bf16x8;
typedef __attribute__((ext_vector_type(4))) float f32x4;
typedef __attribute__((ext_vector_type(8))) unsigned short ushort8;

// Problem constants
constexpr int kB = 64;     // batch
constexpr int kN = 196;    // tokens in X
constexpr int kC = 512;    // X channels
constexpr int kE = 512;    // embedding dim
constexpr int kH = 1024;   // hidden
constexpr int kV = 10000;  // vocab (= 625*16 exactly)
constexpr int kT = 20;     // steps
constexpr int kG4 = 4 * kH;   // 4096
constexpr int kKA = 1536;     // activation K (e|h)
constexpr int kLT = 625;      // logit col-tiles of 16

__device__ __forceinline__ float sigmoidf_(float x) { return 1.0f / (1.0f + expf(-x)); }

__device__ __forceinline__ u16 f2bf(float x) {
    unsigned u = __float_as_uint(x);
    u += 0x7FFF + ((u >> 16) & 1);
    return (u16)(u >> 16);
}
__device__ __forceinline__ float bf2f(u16 u) {
    return __uint_as_float((unsigned)u << 16);
}
__device__ __forceinline__ void splitbf(float x, u16& hi, u16& lo) {
    hi = f2bf(x);
    lo = f2bf(x - bf2f(hi));
}

// online-softmax partial merge; ties -> lower index (matches np.argmax)
__device__ __forceinline__ void mergeMS(float& M, float& S, int& I,
                                        float m2, float s2, int i2) {
    float Mn = fmaxf(M, m2);
    S = S * __expf(M - Mn) + s2 * __expf(m2 - Mn);
    if (m2 > M || (m2 == M && i2 < I)) I = i2;
    M = Mn;
}

// ---------------- setup kernels (run once) ----------------

__global__ __launch_bounds__(256) void k_colsum(const float* __restrict__ X,
                                                float* __restrict__ XsP) {
    int gid = blockIdx.x * 256 + threadIdx.x;    // 4*64*512
    int c = gid & 511, b = (gid >> 9) & 63, ch = gid >> 15;
    const float* p = X + (size_t)b * kN * kC + (size_t)(ch * 49) * kC + c;
    float s = 0.f;
    for (int n = 0; n < 49; ++n) s += p[(size_t)n * kC];
    XsP[gid] = s;
}

__global__ __launch_bounds__(256) void k_colred(const float* __restrict__ XsP,
                                                float* __restrict__ XsT) {
    int gid = blockIdx.x * 256 + threadIdx.x;    // 64*512
    int b = gid >> 9, c = gid & 511;
    float s = 0.f;
#pragma unroll
    for (int ch = 0; ch < 4; ++ch) s += XsP[ch * 32768 + b * 512 + c];
    XsT[c * kB + b] = s;
}

// Unified fp32 setup GEMM from XsT (K=512).
__global__ __launch_bounds__(256) void k_setupgemm(const float* __restrict__ XsT,
                                                   const float* __restrict__ W_ih,
                                                   const float* __restrict__ b_ih,
                                                   const float* __restrict__ b_hh,
                                                   const float* __restrict__ Wc0,
                                                   const float* __restrict__ bc0,
                                                   const float* __restrict__ Wh0,
                                                   const float* __restrict__ bh0,
                                                   const float* __restrict__ Wlc,
                                                   const float* __restrict__ blc,
                                                   const float* __restrict__ blh,
                                                   float* __restrict__ gbP,
                                                   float* __restrict__ cBJ,
                                                   u16* __restrict__ Ab0Hi,
                                                   u16* __restrict__ Ab0Lo,
                                                   float* __restrict__ ctxc) {
    __shared__ float4 wt4[64][8];
    int t = threadIdx.x;
    int b = t & 63, q = t >> 6;
    int tile = blockIdx.x;

    const float* W; const float* bias; float scale; int ldw; int mode; int j;
    if (tile < 128) {
        j = tile * 32; W = W_ih + (size_t)kE * kG4 + j; ldw = kG4;
        bias = nullptr; scale = 1.f; mode = 0;
    } else if (tile < 160) {
        j = (tile - 128) * 32; W = Wc0 + j; ldw = kH;
        bias = bc0 + j; scale = 1.0f / 196.0f; mode = 1;
    } else if (tile < 192) {
        j = (tile - 160) * 32; W = Wh0 + j; ldw = kH;
        bias = bh0 + j; scale = 1.0f / 196.0f; mode = 2;
    } else {
        j = (tile - 192) * 32; W = Wlc + j; ldw = kE;
        bias = blc + j; scale = 1.f; mode = 3;
    }

    int lr = t >> 2, lq2 = (t & 3) * 2;
    float acc[8];
#pragma unroll
    for (int i = 0; i < 8; ++i) acc[i] = 0.f;

    for (int kt = 0; kt < kC; kt += 64) {
        const float* wrow = W + (size_t)(kt + lr) * ldw;
        float4 w0 = *reinterpret_cast<const float4*>(wrow + lq2 * 4);
        float4 w1 = *reinterpret_cast<const float4*>(wrow + lq2 * 4 + 4);
        __syncthreads();
        wt4[lr][lq2] = w0; wt4[lr][lq2 + 1] = w1;
        __syncthreads();
        const float* ap = XsT + (size_t)kt * kB + b;
#pragma unroll 8
        for (int kk = 0; kk < 64; ++kk) {
            float a = ap[kk * 64] * scale;
            float4 u0 = wt4[kk][q * 2];
            float4 u1 = wt4[kk][q * 2 + 1];
            acc[0] += a * u0.x; acc[1] += a * u0.y; acc[2] += a * u0.z; acc[3] += a * u0.w;
            acc[4] += a * u1.x; acc[5] += a * u1.y; acc[6] += a * u1.z; acc[7] += a * u1.w;
        }
    }
#pragma unroll
    for (int cc = 0; cc < 8; ++cc) {
        int col = q * 8 + cc;
        float v = acc[cc];
        if (mode == 0) {
            int jsrc = j + col;
            v += b_ih[jsrc] + b_hh[jsrc];
            int nd = ((jsrc & 1023) << 2) | (jsrc >> 10);   // gate-interleave perm
            gbP[(size_t)b * kG4 + nd] = v;
        } else if (mode == 1) {
            v = tanhf(v + bias[col]);
            cBJ[(size_t)b * kH + j + col] = v;
        } else if (mode == 2) {
            v = tanhf(v + bias[col]);
            u16 hi, lo; splitbf(v, hi, lo);
            Ab0Hi[(size_t)b * kKA + kE + j + col] = hi;
            Ab0Lo[(size_t)b * kKA + kE + j + col] = lo;
        } else {
            v += bias[col] + blh[j + col];
            ctxc[(size_t)b * kE + j + col] = v;
        }
    }
}

// transpose + bf16 hi/lo split: dst[n][k] from src[k][n]  (generic)
__global__ __launch_bounds__(256) void k_wconv(const float* __restrict__ src,
                                               u16* __restrict__ dhi,
                                               u16* __restrict__ dlo,
                                               int ld, int n_valid, int pitch,
                                               int k_off, int nxTiles) {
    __shared__ float lds[64][65];
    int t = threadIdx.x;
    int nx = blockIdx.x % nxTiles, ky = blockIdx.x / nxTiles;
    int n0 = nx * 64, k0 = ky * 64;
    int c = t & 63, r0 = t >> 6;
#pragma unroll
    for (int i = 0; i < 16; ++i) {
        int r = r0 + i * 4;
        float v = (n0 + c < n_valid) ? src[(size_t)(k0 + r) * ld + n0 + c] : 0.f;
        lds[r][c] = v;
    }
    __syncthreads();
    int nl = t >> 2, kq = t & 3;
#pragma unroll
    for (int half = 0; half < 2; ++half) {
        ushort8 vh, vl;
#pragma unroll
        for (int jj = 0; jj < 8; ++jj) {
            u16 hi, lo; splitbf(lds[kq * 16 + half * 8 + jj][nl], hi, lo);
            vh[jj] = hi; vl[jj] = lo;
        }
        size_t o = (size_t)(n0 + nl) * pitch + k_off + k0 + kq * 16 + half * 8;
        *(ushort8*)(&dhi[o]) = vh;
        *(ushort8*)(&dlo[o]) = vl;
    }
}

// gate-interleaved transpose+split for Wg: dst col n = 4*j' + gate
__global__ __launch_bounds__(256) void k_wgconv(const float* __restrict__ src,
                                                u16* __restrict__ dhi,
                                                u16* __restrict__ dlo,
                                                int k_off) {
    __shared__ float lds[64][65];
    int t = threadIdx.x;
    int nx = blockIdx.x & 63, ky = blockIdx.x >> 6;
    int n0 = nx * 64, k0 = ky * 64;
    int c = t & 63, r0 = t >> 6;
#pragma unroll
    for (int i = 0; i < 16; ++i) {
        int r = r0 + i * 4;
        int nd = n0 + c;
        int nsrc = (nd & 3) * 1024 + (nd >> 2);
        lds[r][c] = src[(size_t)(k0 + r) * kG4 + nsrc];
    }
    __syncthreads();
    int nl = t >> 2, kq = t & 3;
#pragma unroll
    for (int half = 0; half < 2; ++half) {
        ushort8 vh, vl;
#pragma unroll
        for (int jj = 0; jj < 8; ++jj) {
            u16 hi, lo; splitbf(lds[kq * 16 + half * 8 + jj][nl], hi, lo);
            vh[jj] = hi; vl[jj] = lo;
        }
        size_t o = (size_t)(n0 + nl) * kKA + k_off + k0 + kq * 16 + half * 8;
        *(ushort8*)(&dhi[o]) = vh;
        *(ushort8*)(&dlo[o]) = vl;
    }
}

// e-slot init: emb[START_IDX=1] into BOTH Ab buffers
__global__ __launch_bounds__(256) void k_emb0(const float* __restrict__ emb,
                                              u16* __restrict__ h0, u16* __restrict__ l0,
                                              u16* __restrict__ h1, u16* __restrict__ l1) {
    int gid = blockIdx.x * 256 + threadIdx.x;      // 64*512
    int b = gid >> 9, k = gid & 511;
    u16 hi, lo; splitbf(emb[kE + k], hi, lo);
    size_t o = (size_t)b * kKA + k;
    h0[o] = hi; l0[o] = lo; h1[o] = hi; l1[o] = lo;
}

__global__ __launch_bounds__(256) void k_out0(float* __restrict__ out) {
    int gid = blockIdx.x * 256 + threadIdx.x;      // 64*10000
    if (gid >= kB * kV) return;
    int b = gid / kV, v = gid - b * kV;
    out[(size_t)b * kT * kV + v] = (v == 1) ? 1.0f : 0.0f;
}

// ---------------- phase device code (shared by coop + fallback) ----------------

struct LoopP {
    u16 *AbHi0, *AbLo0, *AbHi1, *AbLo1;
    float *cBJ, *gbP, *ctxc;
    u16 *CbHi, *CbLo;
    const u16 *WgHi, *WgLo, *WlhHi, *WlhLo, *WoHi, *WoLo;
    const float *bout, *emb;
    float *lbuf, *lse, *LpM, *LpS;
    int *LpI;
    float *out;
};

struct SharedT {
    float sred[4][64][17];
    float redM[256];
    float redS[256];
    int   redI[256];
};

// Phase G: gates GEMM (K=1536, wave-split-K) + LSTM. Uses blocks [0,256).
__device__ __forceinline__ void phaseG(const LoopP& p, int step, SharedT& sm) {
    const int blk = blockIdx.x, t = threadIdx.x;
    if (blk >= 256) return;
    const int l = t & 63, w = t >> 6, la = l & 15, lg = l >> 4;
    const int Pb = (step - 1) & 1, Qb = step & 1;
    const u16* aHi = Pb ? p.AbHi1 : p.AbHi0;
    const u16* aLo = Pb ? p.AbLo1 : p.AbLo0;
    u16* nHi = Qb ? p.AbHi1 : p.AbHi0;
    u16* nLo = Qb ? p.AbLo1 : p.AbLo0;
    const int n0 = blk * 16;
    const int kb = w * 384 + lg * 8;
    const u16* wh = p.WgHi + (size_t)(n0 + la) * kKA + kb;
    const u16* wl = p.WgLo + (size_t)(n0 + la) * kKA + kb;
    const u16* a0h = aHi + (size_t)la * kKA + kb;
    const u16* a0l = aLo + (size_t)la * kKA + kb;

    f32x4 acc[4];
#pragma unroll
    for (int m = 0; m < 4; ++m) acc[m] = (f32x4){0.f, 0.f, 0.f, 0.f};
    for (int ks = 0; ks < 12; ++ks) {
        int ko = ks * 32;
        bf16x8 bhi = *(const bf16x8*)(wh + ko);
        bf16x8 blo = *(const bf16x8*)(wl + ko);
#pragma unroll
        for (int m = 0; m < 4; ++m) {
            bf16x8 ahi8 = *(const bf16x8*)(a0h + (size_t)m * 16 * kKA + ko);
            bf16x8 alo8 = *(const bf16x8*)(a0l + (size_t)m * 16 * kKA + ko);
            acc[m] = __builtin_amdgcn_mfma_f32_16x16x32_bf16(ahi8, bhi, acc[m], 0, 0, 0);
            acc[m] = __builtin_amdgcn_mfma_f32_16x16x32_bf16(ahi8, blo, acc[m], 0, 0, 0);
            acc[m] = __builtin_amdgcn_mfma_f32_16x16x32_bf16(alo8, bhi, acc[m], 0, 0, 0);
        }
    }
#pragma unroll
    for (int m = 0; m < 4; ++m)
#pragma unroll
        for (int r = 0; r < 4; ++r)
            sm.sred[w][m * 16 + lg * 4 + r][la] = acc[m][r];
    __syncthreads();
    // LSTM: thread (b=l, jl=w) handles hidden j' = blk*4+jl (4 gates adjacent)
    int b = l, jl = w;
    float g[4];
#pragma unroll
    for (int gi = 0; gi < 4; ++gi) {
        int cc = jl * 4 + gi;
        g[gi] = sm.sred[0][b][cc] + sm.sred[1][b][cc] + sm.sred[2][b][cc] + sm.sred[3][b][cc]
              + p.gbP[(size_t)b * kG4 + n0 + cc];
    }
    int jp = blk * 4 + jl;
    float cold = p.cBJ[b * kH + jp];
    float c2 = sigmoidf_(g[1]) * cold + sigmoidf_(g[0]) * tanhf(g[2]);
    float h2 = sigmoidf_(g[3]) * tanhf(c2);
    p.cBJ[b * kH + jp] = c2;
    u16 hh, hl; splitbf(h2, hh, hl);
    nHi[(size_t)b * kKA + kE + jp] = hh;
    nLo[(size_t)b * kKA + kE + jp] = hl;
}

// Phase C: comb GEMM on blocks [0,32); O-write of previous step's row on the rest.
__device__ __forceinline__ void phaseC(const LoopP& p, int step, SharedT& sm) {
    const int blk = blockIdx.x, t = threadIdx.x;
    const int Qb = step & 1;
    const u16* aHi = Qb ? p.AbHi1 : p.AbHi0;
    const u16* aLo = Qb ? p.AbLo1 : p.AbLo0;
    if (blk < 32) {
        const int l = t & 63, w = t >> 6, la = l & 15, lg = l >> 4;
        const int n0 = blk * 16;
        const int kb = w * 256 + lg * 8;
        const u16* wh = p.WlhHi + (size_t)(n0 + la) * kH + kb;
        const u16* wl = p.WlhLo + (size_t)(n0 + la) * kH + kb;
        const u16* a0h = aHi + (size_t)la * kKA + kE + kb;
        const u16* a0l = aLo + (size_t)la * kKA + kE + kb;
        f32x4 acc[4];
#pragma unroll
        for (int m = 0; m < 4; ++m) acc[m] = (f32x4){0.f, 0.f, 0.f, 0.f};
        for (int ks = 0; ks < 8; ++ks) {
            int ko = ks * 32;
            bf16x8 bhi = *(const bf16x8*)(wh + ko);
            bf16x8 blo = *(const bf16x8*)(wl + ko);
#pragma unroll
            for (int m = 0; m < 4; ++m) {
                bf16x8 ahi8 = *(const bf16x8*)(a0h + (size_t)m * 16 * kKA + ko);
                bf16x8 alo8 = *(const bf16x8*)(a0l + (size_t)m * 16 * kKA + ko);
                acc[m] = __builtin_amdgcn_mfma_f32_16x16x32_bf16(ahi8, bhi, acc[m], 0, 0, 0);
                acc[m] = __builtin_amdgcn_mfma_f32_16x16x32_bf16(ahi8, blo, acc[m], 0, 0, 0);
                acc[m] = __builtin_amdgcn_mfma_f32_16x16x32_bf16(alo8, bhi, acc[m], 0, 0, 0);
            }
        }
#pragma unroll
        for (int m = 0; m < 4; ++m)
#pragma unroll
            for (int r = 0; r < 4; ++r)
                sm.sred[w][m * 16 + lg * 4 + r][la] = acc[m][r];
        __syncthreads();
        int b = l, cq = w;
#pragma unroll
        for (int i = 0; i < 4; ++i) {
            int cc = cq * 4 + i;
            int col = n0 + cc;
            float v = sm.sred[0][b][cc] + sm.sred[1][b][cc] + sm.sred[2][b][cc] + sm.sred[3][b][cc];
            v += bf2f(aHi[(size_t)b * kKA + col]) + bf2f(aLo[(size_t)b * kKA + col]);
            v += p.ctxc[(size_t)b * kE + col];
            u16 hh, hl; splitbf(v, hh, hl);
            p.CbHi[(size_t)b * kE + col] = hh;
            p.CbLo[(size_t)b * kE + col] = hl;
        }
    } else if (step > 1) {
        int stride = ((int)gridDim.x - 32) * 256;
        for (int idx = (blk - 32) * 256 + t; idx < kB * kV; idx += stride) {
            int b = idx / kV, c = idx - b * kV;
            p.out[((size_t)b * kT + (step - 1)) * kV + c] = p.lbuf[(size_t)b * kV + c] - p.lse[b];
        }
    }
}

// Phase L: logits GEMM + online (max,sumexp,argmax) partials; grid-strided over 625 tiles.
__device__ __forceinline__ void phaseL(const LoopP& p, SharedT& sm) {
    const int t = threadIdx.x;
    const int l = t & 63, w = t >> 6, la = l & 15, lg = l >> 4;
    for (int tile = blockIdx.x; tile < kLT; tile += gridDim.x) {
        __syncthreads();
        const int c0 = tile * 16;
        const int kb = w * 128 + lg * 8;
        const u16* wh = p.WoHi + (size_t)(c0 + la) * kE + kb;
        const u16* wl = p.WoLo + (size_t)(c0 + la) * kE + kb;
        const u16* a0h = p.CbHi + (size_t)la * kE + kb;
        const u16* a0l = p.CbLo + (size_t)la * kE + kb;
        f32x4 acc[4];
#pragma unroll
        for (int m = 0; m < 4; ++m) acc[m] = (f32x4){0.f, 0.f, 0.f, 0.f};
#pragma unroll
        for (int ks = 0; ks < 4; ++ks) {
            int ko = ks * 32;
            bf16x8 bhi = *(const bf16x8*)(wh + ko);
            bf16x8 blo = *(const bf16x8*)(wl + ko);
#pragma unroll
            for (int m = 0; m < 4; ++m) {
                bf16x8 ahi8 = *(const bf16x8*)(a0h + (size_t)m * 16 * kE + ko);
                bf16x8 alo8 = *(const bf16x8*)(a0l + (size_t)m * 16 * kE + ko);
                acc[m] = __builtin_amdgcn_mfma_f32_16x16x32_bf16(ahi8, bhi, acc[m], 0, 0, 0);
                acc[m] = __builtin_amdgcn_mfma_f32_16x16x32_bf16(ahi8, blo, acc[m], 0, 0, 0);
                acc[m] = __builtin_amdgcn_mfma_f32_16x16x32_bf16(alo8, bhi, acc[m], 0, 0, 0);
            }
        }
#pragma unroll
        for (int m = 0; m < 4; ++m)
#pragma unroll
            for (int r = 0; r < 4; ++r)
                sm.sred[w][m * 16 + lg * 4 + r][la] = acc[m][r];
        __syncthreads();
        int b = l, cq = w;
        float vals[4];
#pragma unroll
        for (int i = 0; i < 4; ++i) {
            int cc = cq * 4 + i;
            vals[i] = sm.sred[0][b][cc] + sm.sred[1][b][cc] + sm.sred[2][b][cc] + sm.sred[3][b][cc]
                    + p.bout[c0 + cc];
        }
        *(float4*)(p.lbuf + (size_t)b * kV + c0 + cq * 4) =
            make_float4(vals[0], vals[1], vals[2], vals[3]);
        float m = vals[0]; int mi = 0;
#pragma unroll
        for (int i = 1; i < 4; ++i) if (vals[i] > m) { m = vals[i]; mi = i; }
        float se = 0.f;
#pragma unroll
        for (int i = 0; i < 4; ++i) se += __expf(vals[i] - m);
        sm.redM[t] = m; sm.redS[t] = se; sm.redI[t] = c0 + cq * 4 + mi;
        __syncthreads();
        if (t < 64) {
            float M = sm.redM[t], S = sm.redS[t]; int I = sm.redI[t];
#pragma unroll
            for (int q2 = 1; q2 < 4; ++q2)
                mergeMS(M, S, I, sm.redM[t + q2 * 64], sm.redS[t + q2 * 64], sm.redI[t + q2 * 64]);
            p.LpM[tile * 64 + t] = M; p.LpS[tile * 64 + t] = S; p.LpI[tile * 64 + t] = I;
        }
    }
}

// Phase F1: merge partials -> lse, token; gather next e into BOTH Ab buffers. Blocks [0,64).
__device__ __forceinline__ void phaseF1(const LoopP& p, SharedT& sm) {
    const int blk = blockIdx.x, t = threadIdx.x;
    if (blk >= 64) return;
    int b = blk;
    float M = -3.4e38f, S = 0.f; int I = 0;
    for (int j = t; j < kLT; j += 256)
        mergeMS(M, S, I, p.LpM[j * 64 + b], p.LpS[j * 64 + b], p.LpI[j * 64 + b]);
    sm.redM[t] = M; sm.redS[t] = S; sm.redI[t] = I;
    __syncthreads();
    for (int s2 = 128; s2 > 0; s2 >>= 1) {
        if (t < s2) {
            float M1 = sm.redM[t], S1 = sm.redS[t]; int I1 = sm.redI[t];
            mergeMS(M1, S1, I1, sm.redM[t + s2], sm.redS[t + s2], sm.redI[t + s2]);
            sm.redM[t] = M1; sm.redS[t] = S1; sm.redI[t] = I1;
        }
        __syncthreads();
    }
    if (t == 0) p.lse[b] = sm.redM[0] + logf(sm.redS[0]);
    int tok = sm.redI[0];
    for (int k2 = t; k2 < kE; k2 += 256) {
        u16 hh, hl; splitbf(p.emb[(size_t)tok * kE + k2], hh, hl);
        size_t o = (size_t)b * kKA + k2;
        p.AbHi0[o] = hh; p.AbLo0[o] = hl;
        p.AbHi1[o] = hh; p.AbLo1[o] = hl;
    }
}

// final O-row (step kT-1)
__device__ __forceinline__ void finalO(const LoopP& p) {
    for (int idx = blockIdx.x * 256 + threadIdx.x; idx < kB * kV; idx += gridDim.x * 256) {
        int b = idx / kV, c = idx - b * kV;
        p.out[((size_t)b * kT + (kT - 1)) * kV + c] = p.lbuf[(size_t)b * kV + c] - p.lse[b];
    }
}

// ---------------- cooperative loop kernel + fallback phase kernels ----------------

__global__ __launch_bounds__(256, 2) void k_loop(LoopP p) {
    cg::grid_group gg = cg::this_grid();
    __shared__ SharedT sm;
    for (int step = 1; step < kT; ++step) {
        phaseG(p, step, sm);
        gg.sync();
        phaseC(p, step, sm);
        gg.sync();
        phaseL(p, sm);
        gg.sync();
        phaseF1(p, sm);
        gg.sync();
    }
    finalO(p);
}

__global__ __launch_bounds__(256, 2) void kP_G(LoopP p, int step) {
    __shared__ SharedT sm; phaseG(p, step, sm);
}
__global__ __launch_bounds__(256, 2) void kP_C(LoopP p, int step) {
    __shared__ SharedT sm; phaseC(p, step, sm);
}
__global__ __launch_bounds__(256, 2) void kP_L(LoopP p) {
    __shared__ SharedT sm; phaseL(p, sm);
}
__global__ __launch_bounds__(256, 2) void kP_F1(LoopP p) {
    __shared__ SharedT sm; phaseF1(p, sm);
}
__global__ __launch_bounds__(256, 2) void kP_O(LoopP p) { finalO(p); }

// ---------------- launcher ----------------

extern "C" void kernel_launch(void* const* d_in, const int* in_sizes, int n_in,
                              void* d_out, int out_size, void* d_ws, size_t ws_size,
                              hipStream_t stream) {
    const float* X    = (const float*)d_in[0];
    const float* emb  = (const float*)d_in[1];
    const float* W_ih = (const float*)d_in[2];
    const float* b_ih = (const float*)d_in[3];
    const float* W_hh = (const float*)d_in[4];
    const float* b_hh = (const float*)d_in[5];
    // d_in[6..11]: Wa, ba, Wh, bh, Wo, bo — dead (softmax over size-1 axis => weights==1)
    const float* Wlh  = (const float*)d_in[12];
    const float* blh  = (const float*)d_in[13];
    const float* Wlc  = (const float*)d_in[14];
    const float* blc  = (const float*)d_in[15];
    const float* Wout = (const float*)d_in[16];
    const float* bout = (const float*)d_in[17];
    const float* Wc0  = (const float*)d_in[18];
    const float* bc0  = (const float*)d_in[19];
    const float* Wh0  = (const float*)d_in[20];
    const float* bh0  = (const float*)d_in[21];
    float* out = (float*)d_out;

    char* cur = (char*)d_ws;
    auto carve = [&](size_t bytes) { char* p = cur; cur += (bytes + 255) & ~(size_t)255; return p; };

    u16* AbHi0 = (u16*)carve((size_t)kB * kKA * 2);
    u16* AbLo0 = (u16*)carve((size_t)kB * kKA * 2);
    u16* AbHi1 = (u16*)carve((size_t)kB * kKA * 2);
    u16* AbLo1 = (u16*)carve((size_t)kB * kKA * 2);
    float* cBJ  = (float*)carve((size_t)kB * kH * 4);
    float* gbP  = (float*)carve((size_t)kB * kG4 * 4);
    float* ctxc = (float*)carve((size_t)kB * kE * 4);
    u16* CbHi   = (u16*)carve((size_t)kB * kE * 2);
    u16* CbLo   = (u16*)carve((size_t)kB * kE * 2);
    float* XsT  = (float*)carve((size_t)kC * kB * 4);
    float* XsP  = (float*)carve((size_t)4 * kB * kC * 4);
    u16* WgHi   = (u16*)carve((size_t)kG4 * kKA * 2);
    u16* WgLo   = (u16*)carve((size_t)kG4 * kKA * 2);
    u16* WlhHi  = (u16*)carve((size_t)kE * kH * 2);
    u16* WlhLo  = (u16*)carve((size_t)kE * kH * 2);
    u16* WoHi   = (u16*)carve((size_t)10048 * kE * 2);
    u16* WoLo   = (u16*)carve((size_t)10048 * kE * 2);
    float* lbuf = (float*)carve((size_t)kB * kV * 4);
    float* lse  = (float*)carve((size_t)kB * 4);
    float* LpM  = (float*)carve((size_t)kLT * kB * 4);
    float* LpS  = (float*)carve((size_t)kLT * kB * 4);
    int*   LpI  = (int*)carve((size_t)kLT * kB * 4);

    // one-time setup
    k_colsum<<<512, 256, 0, stream>>>(X, XsP);
    k_colred<<<128, 256, 0, stream>>>(XsP, XsT);
    k_setupgemm<<<208, 256, 0, stream>>>(XsT, W_ih, b_ih, b_hh, Wc0, bc0,
                                         Wh0, bh0, Wlc, blc, blh,
                                         gbP, cBJ, AbHi0, AbLo0, ctxc);
    k_emb0<<<128, 256, 0, stream>>>(emb, AbHi0, AbLo0, AbHi1, AbLo1);
    k_out0<<<(kB * kV + 255) / 256, 256, 0, stream>>>(out);
    k_wgconv<<<64 * 8, 256, 0, stream>>>(W_ih, WgHi, WgLo, 0);     // k 0..511 (e)
    k_wgconv<<<64 * 16, 256, 0, stream>>>(W_hh, WgHi, WgLo, kE);   // k 512..1535 (h)
    k_wconv<<<8 * 16, 256, 0, stream>>>(Wlh, WlhHi, WlhLo, kE, kE, kH, 0, 8);
    k_wconv<<<157 * 8, 256, 0, stream>>>(Wout, WoHi, WoLo, kV, kV, kE, 0, 157);

    LoopP lp;
    lp.AbHi0 = AbHi0; lp.AbLo0 = AbLo0; lp.AbHi1 = AbHi1; lp.AbLo1 = AbLo1;
    lp.cBJ = cBJ; lp.gbP = gbP; lp.ctxc = ctxc;
    lp.CbHi = CbHi; lp.CbLo = CbLo;
    lp.WgHi = WgHi; lp.WgLo = WgLo; lp.WlhHi = WlhHi; lp.WlhLo = WlhLo;
    lp.WoHi = WoHi; lp.WoLo = WoLo;
    lp.bout = bout; lp.emb = emb;
    lp.lbuf = lbuf; lp.lse = lse; lp.LpM = LpM; lp.LpS = LpS; lp.LpI = LpI;
    lp.out = out;
    void* args[] = {&lp};

    // try cooperative at 512 blocks (2/CU), then 256 (1/CU); else phase-kernel fallback
    hipError_t cerr = hipLaunchCooperativeKernel((void*)k_loop, dim3(512), dim3(256),
                                                 args, 0, stream);
    if (cerr != hipSuccess)
        cerr = hipLaunchCooperativeKernel((void*)k_loop, dim3(256), dim3(256),
                                          args, 0, stream);
    if (cerr != hipSuccess) {
        for (int s = 1; s < kT; ++s) {
            kP_G<<<256, 256, 0, stream>>>(lp, s);
            kP_C<<<625, 256, 0, stream>>>(lp, s);
            kP_L<<<625, 256, 0, stream>>>(lp);
            kP_F1<<<64, 256, 0, stream>>>(lp);
        }
        kP_O<<<625, 256, 0, stream>>>(lp);
    }
}

// Round 9
// 3324.803 us; speedup vs baseline: 1.6226x; 1.6226x over previous
//
#include <hip/hip_runtime.h>
#include <math.h>

typedef unsigned short u16;
typedef __attribute__((ext_vector_type(8))) short bf16x8;
typedef __attribute__((ext_vector_type(4))) float f32x4;
typedef __attribute__((ext_vector_type(8))) unsigned short ushort8;

// Problem constants
constexpr int kB = 64;     // batch
constexpr int kN = 196;    // tokens in X
constexpr int kC = 512;    // X channels
constexpr int kE = 512;    // embedding dim
constexpr int kH = 1024;   // hidden
constexpr int kV = 10000;  // vocab (= 625*16 exactly)
constexpr int kT = 20;     // steps
constexpr int kG4 = 4 * kH;   // 4096
constexpr int kKA = 1536;     // activation K (e|h)
constexpr int kLT = 625;      // logit col-tiles of 16
constexpr int kGrid = 512;    // persistent grid (2 blocks/CU, all co-resident)

__device__ __forceinline__ float sigmoidf_(float x) { return 1.0f / (1.0f + expf(-x)); }

__device__ __forceinline__ u16 f2bf(float x) {
    unsigned u = __float_as_uint(x);
    u += 0x7FFF + ((u >> 16) & 1);
    return (u16)(u >> 16);
}
__device__ __forceinline__ float bf2f(u16 u) {
    return __uint_as_float((unsigned)u << 16);
}
__device__ __forceinline__ void splitbf(float x, u16& hi, u16& lo) {
    hi = f2bf(x);
    lo = f2bf(x - bf2f(hi));
}

// online-softmax partial merge; ties -> lower index (matches np.argmax)
__device__ __forceinline__ void mergeMS(float& M, float& S, int& I,
                                        float m2, float s2, int i2) {
    float Mn = fmaxf(M, m2);
    S = S * __expf(M - Mn) + s2 * __expf(m2 - Mn);
    if (m2 > M || (m2 == M && i2 < I)) I = i2;
    M = Mn;
}

// ---- flag-barrier primitives (agent scope, relaxed polls + one fence) ----
__device__ __forceinline__ void bumpCtr(int* c) {
    __syncthreads();
    if (threadIdx.x == 0) {
        __builtin_amdgcn_fence(__ATOMIC_RELEASE, "agent");
        __hip_atomic_fetch_add(c, 1, __ATOMIC_RELAXED, __HIP_MEMORY_SCOPE_AGENT);
    }
}
__device__ __forceinline__ void waitGE(const int* c, int target) {
    // bounded spin: breaks (wrong answer, not hang) if a logic bug deadlocks
    int it = 0;
    while (__hip_atomic_load(c, __ATOMIC_RELAXED, __HIP_MEMORY_SCOPE_AGENT) < target
           && it < (1 << 22)) {
        __builtin_amdgcn_s_sleep(4);
        ++it;
    }
    __builtin_amdgcn_fence(__ATOMIC_ACQUIRE, "agent");
    __syncthreads();
}
// counter slot offsets (separate 128B lines)
constexpr int CT_G = 0, CT_C = 32, CT_L = 64, CT_F = 96, CT_O = 128;

// ---------------- setup kernels (run once) ----------------

__global__ __launch_bounds__(256) void k_colsum(const float* __restrict__ X,
                                                float* __restrict__ XsP) {
    int gid = blockIdx.x * 256 + threadIdx.x;    // 4*64*512
    int c = gid & 511, b = (gid >> 9) & 63, ch = gid >> 15;
    const float* p = X + (size_t)b * kN * kC + (size_t)(ch * 49) * kC + c;
    float s = 0.f;
    for (int n = 0; n < 49; ++n) s += p[(size_t)n * kC];
    XsP[gid] = s;
}

__global__ __launch_bounds__(256) void k_colred(const float* __restrict__ XsP,
                                                float* __restrict__ XsT) {
    int gid = blockIdx.x * 256 + threadIdx.x;    // 64*512
    int b = gid >> 9, c = gid & 511;
    float s = 0.f;
#pragma unroll
    for (int ch = 0; ch < 4; ++ch) s += XsP[ch * 32768 + b * 512 + c];
    XsT[c * kB + b] = s;
}

// Unified fp32 setup GEMM from XsT (K=512).
__global__ __launch_bounds__(256) void k_setupgemm(const float* __restrict__ XsT,
                                                   const float* __restrict__ W_ih,
                                                   const float* __restrict__ b_ih,
                                                   const float* __restrict__ b_hh,
                                                   const float* __restrict__ Wc0,
                                                   const float* __restrict__ bc0,
                                                   const float* __restrict__ Wh0,
                                                   const float* __restrict__ bh0,
                                                   const float* __restrict__ Wlc,
                                                   const float* __restrict__ blc,
                                                   const float* __restrict__ blh,
                                                   float* __restrict__ gbP,
                                                   float* __restrict__ cBJ,
                                                   u16* __restrict__ Ab0Hi,
                                                   u16* __restrict__ Ab0Lo,
                                                   float* __restrict__ ctxc) {
    __shared__ float4 wt4[64][8];
    int t = threadIdx.x;
    int b = t & 63, q = t >> 6;
    int tile = blockIdx.x;

    const float* W; const float* bias; float scale; int ldw; int mode; int j;
    if (tile < 128) {
        j = tile * 32; W = W_ih + (size_t)kE * kG4 + j; ldw = kG4;
        bias = nullptr; scale = 1.f; mode = 0;
    } else if (tile < 160) {
        j = (tile - 128) * 32; W = Wc0 + j; ldw = kH;
        bias = bc0 + j; scale = 1.0f / 196.0f; mode = 1;
    } else if (tile < 192) {
        j = (tile - 160) * 32; W = Wh0 + j; ldw = kH;
        bias = bh0 + j; scale = 1.0f / 196.0f; mode = 2;
    } else {
        j = (tile - 192) * 32; W = Wlc + j; ldw = kE;
        bias = blc + j; scale = 1.f; mode = 3;
    }

    int lr = t >> 2, lq2 = (t & 3) * 2;
    float acc[8];
#pragma unroll
    for (int i = 0; i < 8; ++i) acc[i] = 0.f;

    for (int kt = 0; kt < kC; kt += 64) {
        const float* wrow = W + (size_t)(kt + lr) * ldw;
        float4 w0 = *reinterpret_cast<const float4*>(wrow + lq2 * 4);
        float4 w1 = *reinterpret_cast<const float4*>(wrow + lq2 * 4 + 4);
        __syncthreads();
        wt4[lr][lq2] = w0; wt4[lr][lq2 + 1] = w1;
        __syncthreads();
        const float* ap = XsT + (size_t)kt * kB + b;
#pragma unroll 8
        for (int kk = 0; kk < 64; ++kk) {
            float a = ap[kk * 64] * scale;
            float4 u0 = wt4[kk][q * 2];
            float4 u1 = wt4[kk][q * 2 + 1];
            acc[0] += a * u0.x; acc[1] += a * u0.y; acc[2] += a * u0.z; acc[3] += a * u0.w;
            acc[4] += a * u1.x; acc[5] += a * u1.y; acc[6] += a * u1.z; acc[7] += a * u1.w;
        }
    }
#pragma unroll
    for (int cc = 0; cc < 8; ++cc) {
        int col = q * 8 + cc;
        float v = acc[cc];
        if (mode == 0) {
            int jsrc = j + col;
            v += b_ih[jsrc] + b_hh[jsrc];
            int nd = ((jsrc & 1023) << 2) | (jsrc >> 10);   // gate-interleave perm
            gbP[(size_t)b * kG4 + nd] = v;
        } else if (mode == 1) {
            v = tanhf(v + bias[col]);
            cBJ[(size_t)b * kH + j + col] = v;
        } else if (mode == 2) {
            v = tanhf(v + bias[col]);
            u16 hi, lo; splitbf(v, hi, lo);
            Ab0Hi[(size_t)b * kKA + kE + j + col] = hi;
            Ab0Lo[(size_t)b * kKA + kE + j + col] = lo;
        } else {
            v += bias[col] + blh[j + col];
            ctxc[(size_t)b * kE + j + col] = v;
        }
    }
}

// transpose + bf16 hi/lo split: dst[n][k] from src[k][n]  (generic)
__global__ __launch_bounds__(256) void k_wconv(const float* __restrict__ src,
                                               u16* __restrict__ dhi,
                                               u16* __restrict__ dlo,
                                               int ld, int n_valid, int pitch,
                                               int k_off, int nxTiles) {
    __shared__ float lds[64][65];
    int t = threadIdx.x;
    int nx = blockIdx.x % nxTiles, ky = blockIdx.x / nxTiles;
    int n0 = nx * 64, k0 = ky * 64;
    int c = t & 63, r0 = t >> 6;
#pragma unroll
    for (int i = 0; i < 16; ++i) {
        int r = r0 + i * 4;
        float v = (n0 + c < n_valid) ? src[(size_t)(k0 + r) * ld + n0 + c] : 0.f;
        lds[r][c] = v;
    }
    __syncthreads();
    int nl = t >> 2, kq = t & 3;
#pragma unroll
    for (int half = 0; half < 2; ++half) {
        ushort8 vh, vl;
#pragma unroll
        for (int jj = 0; jj < 8; ++jj) {
            u16 hi, lo; splitbf(lds[kq * 16 + half * 8 + jj][nl], hi, lo);
            vh[jj] = hi; vl[jj] = lo;
        }
        size_t o = (size_t)(n0 + nl) * pitch + k_off + k0 + kq * 16 + half * 8;
        *(ushort8*)(&dhi[o]) = vh;
        *(ushort8*)(&dlo[o]) = vl;
    }
}

// gate-interleaved transpose+split for Wg: dst col n = 4*j' + gate
__global__ __launch_bounds__(256) void k_wgconv(const float* __restrict__ src,
                                                u16* __restrict__ dhi,
                                                u16* __restrict__ dlo,
                                                int k_off) {
    __shared__ float lds[64][65];
    int t = threadIdx.x;
    int nx = blockIdx.x & 63, ky = blockIdx.x >> 6;
    int n0 = nx * 64, k0 = ky * 64;
    int c = t & 63, r0 = t >> 6;
#pragma unroll
    for (int i = 0; i < 16; ++i) {
        int r = r0 + i * 4;
        int nd = n0 + c;
        int nsrc = (nd & 3) * 1024 + (nd >> 2);
        lds[r][c] = src[(size_t)(k0 + r) * kG4 + nsrc];
    }
    __syncthreads();
    int nl = t >> 2, kq = t & 3;
#pragma unroll
    for (int half = 0; half < 2; ++half) {
        ushort8 vh, vl;
#pragma unroll
        for (int jj = 0; jj < 8; ++jj) {
            u16 hi, lo; splitbf(lds[kq * 16 + half * 8 + jj][nl], hi, lo);
            vh[jj] = hi; vl[jj] = lo;
        }
        size_t o = (size_t)(n0 + nl) * kKA + k_off + k0 + kq * 16 + half * 8;
        *(ushort8*)(&dhi[o]) = vh;
        *(ushort8*)(&dlo[o]) = vl;
    }
}

// e-slot init: emb[START_IDX=1] into BOTH Ab buffers
__global__ __launch_bounds__(256) void k_emb0(const float* __restrict__ emb,
                                              u16* __restrict__ h0, u16* __restrict__ l0,
                                              u16* __restrict__ h1, u16* __restrict__ l1) {
    int gid = blockIdx.x * 256 + threadIdx.x;      // 64*512
    int b = gid >> 9, k = gid & 511;
    u16 hi, lo; splitbf(emb[kE + k], hi, lo);
    size_t o = (size_t)b * kKA + k;
    h0[o] = hi; l0[o] = lo; h1[o] = hi; l1[o] = lo;
}

__global__ __launch_bounds__(256) void k_out0(float* __restrict__ out) {
    int gid = blockIdx.x * 256 + threadIdx.x;      // 64*10000
    if (gid >= kB * kV) return;
    int b = gid / kV, v = gid - b * kV;
    out[(size_t)b * kT * kV + v] = (v == 1) ? 1.0f : 0.0f;
}

// ---------------- persistent loop kernel ----------------

struct LoopP {
    u16 *AbHi0, *AbLo0, *AbHi1, *AbLo1;
    float *cBJ, *gbP, *ctxc;
    u16 *CbHi, *CbLo;
    const u16 *WgHi, *WgLo, *WlhHi, *WlhLo, *WoHi, *WoLo;
    const float *bout, *emb;
    float *lbuf, *lse, *LpM, *LpS;
    int *LpI;
    float *out;
    int *ctrs;
};

struct SharedT {
    float sred[4][64][17];
    float redM[256];
    float redS[256];
    int   redI[256];
};

// Phase G: gates GEMM (K=1536, wave-split-K) + LSTM. Blocks [0,256).
__device__ __forceinline__ void phaseG(const LoopP& p, int step, SharedT& sm) {
    const int blk = blockIdx.x, t = threadIdx.x;
    const int l = t & 63, w = t >> 6, la = l & 15, lg = l >> 4;
    const int Pb = (step - 1) & 1, Qb = step & 1;
    const u16* aHi = Pb ? p.AbHi1 : p.AbHi0;
    const u16* aLo = Pb ? p.AbLo1 : p.AbLo0;
    u16* nHi = Qb ? p.AbHi1 : p.AbHi0;
    u16* nLo = Qb ? p.AbLo1 : p.AbLo0;
    const int n0 = blk * 16;
    const int kb = w * 384 + lg * 8;
    const u16* wh = p.WgHi + (size_t)(n0 + la) * kKA + kb;
    const u16* wl = p.WgLo + (size_t)(n0 + la) * kKA + kb;
    const u16* a0h = aHi + (size_t)la * kKA + kb;
    const u16* a0l = aLo + (size_t)la * kKA + kb;

    f32x4 acc[4];
#pragma unroll
    for (int m = 0; m < 4; ++m) acc[m] = (f32x4){0.f, 0.f, 0.f, 0.f};
    for (int ks = 0; ks < 12; ++ks) {
        int ko = ks * 32;
        bf16x8 bhi = *(const bf16x8*)(wh + ko);
        bf16x8 blo = *(const bf16x8*)(wl + ko);
#pragma unroll
        for (int m = 0; m < 4; ++m) {
            bf16x8 ahi8 = *(const bf16x8*)(a0h + (size_t)m * 16 * kKA + ko);
            bf16x8 alo8 = *(const bf16x8*)(a0l + (size_t)m * 16 * kKA + ko);
            acc[m] = __builtin_amdgcn_mfma_f32_16x16x32_bf16(ahi8, bhi, acc[m], 0, 0, 0);
            acc[m] = __builtin_amdgcn_mfma_f32_16x16x32_bf16(ahi8, blo, acc[m], 0, 0, 0);
            acc[m] = __builtin_amdgcn_mfma_f32_16x16x32_bf16(alo8, bhi, acc[m], 0, 0, 0);
        }
    }
#pragma unroll
    for (int m = 0; m < 4; ++m)
#pragma unroll
        for (int r = 0; r < 4; ++r)
            sm.sred[w][m * 16 + lg * 4 + r][la] = acc[m][r];
    __syncthreads();
    int b = l, jl = w;
    float g[4];
#pragma unroll
    for (int gi = 0; gi < 4; ++gi) {
        int cc = jl * 4 + gi;
        g[gi] = sm.sred[0][b][cc] + sm.sred[1][b][cc] + sm.sred[2][b][cc] + sm.sred[3][b][cc]
              + p.gbP[(size_t)b * kG4 + n0 + cc];
    }
    int jp = blk * 4 + jl;
    float cold = p.cBJ[b * kH + jp];
    float c2 = sigmoidf_(g[1]) * cold + sigmoidf_(g[0]) * tanhf(g[2]);
    float h2 = sigmoidf_(g[3]) * tanhf(c2);
    p.cBJ[b * kH + jp] = c2;
    u16 hh, hl; splitbf(h2, hh, hl);
    nHi[(size_t)b * kKA + kE + jp] = hh;
    nLo[(size_t)b * kKA + kE + jp] = hl;
}

// Phase C: comb GEMM. Blocks [0,32).
__device__ __forceinline__ void phaseC(const LoopP& p, int step, SharedT& sm) {
    const int blk = blockIdx.x, t = threadIdx.x;
    const int Qb = step & 1;
    const u16* aHi = Qb ? p.AbHi1 : p.AbHi0;
    const u16* aLo = Qb ? p.AbLo1 : p.AbLo0;
    const int l = t & 63, w = t >> 6, la = l & 15, lg = l >> 4;
    const int n0 = blk * 16;
    const int kb = w * 256 + lg * 8;
    const u16* wh = p.WlhHi + (size_t)(n0 + la) * kH + kb;
    const u16* wl = p.WlhLo + (size_t)(n0 + la) * kH + kb;
    const u16* a0h = aHi + (size_t)la * kKA + kE + kb;
    const u16* a0l = aLo + (size_t)la * kKA + kE + kb;
    f32x4 acc[4];
#pragma unroll
    for (int m = 0; m < 4; ++m) acc[m] = (f32x4){0.f, 0.f, 0.f, 0.f};
    for (int ks = 0; ks < 8; ++ks) {
        int ko = ks * 32;
        bf16x8 bhi = *(const bf16x8*)(wh + ko);
        bf16x8 blo = *(const bf16x8*)(wl + ko);
#pragma unroll
        for (int m = 0; m < 4; ++m) {
            bf16x8 ahi8 = *(const bf16x8*)(a0h + (size_t)m * 16 * kKA + ko);
            bf16x8 alo8 = *(const bf16x8*)(a0l + (size_t)m * 16 * kKA + ko);
            acc[m] = __builtin_amdgcn_mfma_f32_16x16x32_bf16(ahi8, bhi, acc[m], 0, 0, 0);
            acc[m] = __builtin_amdgcn_mfma_f32_16x16x32_bf16(ahi8, blo, acc[m], 0, 0, 0);
            acc[m] = __builtin_amdgcn_mfma_f32_16x16x32_bf16(alo8, bhi, acc[m], 0, 0, 0);
        }
    }
#pragma unroll
    for (int m = 0; m < 4; ++m)
#pragma unroll
        for (int r = 0; r < 4; ++r)
            sm.sred[w][m * 16 + lg * 4 + r][la] = acc[m][r];
    __syncthreads();
    int b = l, cq = w;
#pragma unroll
    for (int i = 0; i < 4; ++i) {
        int cc = cq * 4 + i;
        int col = n0 + cc;
        float v = sm.sred[0][b][cc] + sm.sred[1][b][cc] + sm.sred[2][b][cc] + sm.sred[3][b][cc];
        v += bf2f(aHi[(size_t)b * kKA + col]) + bf2f(aLo[(size_t)b * kKA + col]);
        v += p.ctxc[(size_t)b * kE + col];
        u16 hh, hl; splitbf(v, hh, hl);
        p.CbHi[(size_t)b * kE + col] = hh;
        p.CbLo[(size_t)b * kE + col] = hl;
    }
}

// Phase L: logits GEMM + online (max,sumexp,argmax) partials; grid-strided tiles.
__device__ __forceinline__ void phaseL(const LoopP& p, SharedT& sm) {
    const int t = threadIdx.x;
    const int l = t & 63, w = t >> 6, la = l & 15, lg = l >> 4;
    for (int tile = blockIdx.x; tile < kLT; tile += kGrid) {
        __syncthreads();
        const int c0 = tile * 16;
        const int kb = w * 128 + lg * 8;
        const u16* wh = p.WoHi + (size_t)(c0 + la) * kE + kb;
        const u16* wl = p.WoLo + (size_t)(c0 + la) * kE + kb;
        const u16* a0h = p.CbHi + (size_t)la * kE + kb;
        const u16* a0l = p.CbLo + (size_t)la * kE + kb;
        f32x4 acc[4];
#pragma unroll
        for (int m = 0; m < 4; ++m) acc[m] = (f32x4){0.f, 0.f, 0.f, 0.f};
#pragma unroll
        for (int ks = 0; ks < 4; ++ks) {
            int ko = ks * 32;
            bf16x8 bhi = *(const bf16x8*)(wh + ko);
            bf16x8 blo = *(const bf16x8*)(wl + ko);
#pragma unroll
            for (int m = 0; m < 4; ++m) {
                bf16x8 ahi8 = *(const bf16x8*)(a0h + (size_t)m * 16 * kE + ko);
                bf16x8 alo8 = *(const bf16x8*)(a0l + (size_t)m * 16 * kE + ko);
                acc[m] = __builtin_amdgcn_mfma_f32_16x16x32_bf16(ahi8, bhi, acc[m], 0, 0, 0);
                acc[m] = __builtin_amdgcn_mfma_f32_16x16x32_bf16(ahi8, blo, acc[m], 0, 0, 0);
                acc[m] = __builtin_amdgcn_mfma_f32_16x16x32_bf16(alo8, bhi, acc[m], 0, 0, 0);
            }
        }
#pragma unroll
        for (int m = 0; m < 4; ++m)
#pragma unroll
            for (int r = 0; r < 4; ++r)
                sm.sred[w][m * 16 + lg * 4 + r][la] = acc[m][r];
        __syncthreads();
        int b = l, cq = w;
        float vals[4];
#pragma unroll
        for (int i = 0; i < 4; ++i) {
            int cc = cq * 4 + i;
            vals[i] = sm.sred[0][b][cc] + sm.sred[1][b][cc] + sm.sred[2][b][cc] + sm.sred[3][b][cc]
                    + p.bout[c0 + cc];
        }
        *(float4*)(p.lbuf + (size_t)b * kV + c0 + cq * 4) =
            make_float4(vals[0], vals[1], vals[2], vals[3]);
        float m = vals[0]; int mi = 0;
#pragma unroll
        for (int i = 1; i < 4; ++i) if (vals[i] > m) { m = vals[i]; mi = i; }
        float se = 0.f;
#pragma unroll
        for (int i = 0; i < 4; ++i) se += __expf(vals[i] - m);
        sm.redM[t] = m; sm.redS[t] = se; sm.redI[t] = c0 + cq * 4 + mi;
        __syncthreads();
        if (t < 64) {
            float M = sm.redM[t], S = sm.redS[t]; int I = sm.redI[t];
#pragma unroll
            for (int q2 = 1; q2 < 4; ++q2)
                mergeMS(M, S, I, sm.redM[t + q2 * 64], sm.redS[t + q2 * 64], sm.redI[t + q2 * 64]);
            p.LpM[tile * 64 + t] = M; p.LpS[tile * 64 + t] = S; p.LpI[tile * 64 + t] = I;
        }
    }
}

// Phase F1: merge partials -> lse, token; gather next e into BOTH Ab buffers. Blocks [0,64).
__device__ __forceinline__ void phaseF1(const LoopP& p, SharedT& sm) {
    const int blk = blockIdx.x, t = threadIdx.x;
    int b = blk;
    float M = -3.4e38f, S = 0.f; int I = 0;
    for (int j = t; j < kLT; j += 256)
        mergeMS(M, S, I, p.LpM[j * 64 + b], p.LpS[j * 64 + b], p.LpI[j * 64 + b]);
    sm.redM[t] = M; sm.redS[t] = S; sm.redI[t] = I;
    __syncthreads();
    for (int s2 = 128; s2 > 0; s2 >>= 1) {
        if (t < s2) {
            float M1 = sm.redM[t], S1 = sm.redS[t]; int I1 = sm.redI[t];
            mergeMS(M1, S1, I1, sm.redM[t + s2], sm.redS[t + s2], sm.redI[t + s2]);
            sm.redM[t] = M1; sm.redS[t] = S1; sm.redI[t] = I1;
        }
        __syncthreads();
    }
    if (t == 0) p.lse[b] = sm.redM[0] + logf(sm.redS[0]);
    int tok = sm.redI[0];
    for (int k2 = t; k2 < kE; k2 += 256) {
        u16 hh, hl; splitbf(p.emb[(size_t)tok * kE + k2], hh, hl);
        size_t o = (size_t)b * kKA + k2;
        p.AbHi0[o] = hh; p.AbLo0[o] = hl;
        p.AbHi1[o] = hh; p.AbLo1[o] = hl;
    }
}

__global__ __launch_bounds__(256, 2) void k_loop(LoopP p) {
    __shared__ SharedT sm;
    const int blk = blockIdx.x, t = threadIdx.x;
    int* ctr = p.ctrs;

    for (int step = 1; step < kT; ++step) {
        if (blk < 256) {
            // G: wait for F1 of previous step (e-part of both Ab buffers final)
            waitGE(ctr + CT_F, 64 * (step - 1));
            phaseG(p, step, sm);
            bumpCtr(ctr + CT_G);
            if (blk < 32) {
                waitGE(ctr + CT_G, 256 * step);
                phaseC(p, step, sm);
                bumpCtr(ctr + CT_C);
            }
        } else {
            // OW: write out row step-1 (needs lbuf/lse of step-1, final after F1[step-1])
            if (step > 1) {
                waitGE(ctr + CT_F, 64 * (step - 1));
                for (int idx = (blk - 256) * 256 + t; idx < kB * kV; idx += 256 * 256) {
                    int b = idx / kV, c = idx - b * kV;
                    p.out[((size_t)b * kT + (step - 1)) * kV + c] =
                        p.lbuf[(size_t)b * kV + c] - p.lse[b];
                }
                bumpCtr(ctr + CT_O);
            }
        }
        // L: needs Cb of this step AND all out-writes of row step-1 done (lbuf overwrite)
        waitGE(ctr + CT_C, 32 * step);
        waitGE(ctr + CT_O, 256 * (step - 1));
        phaseL(p, sm);
        bumpCtr(ctr + CT_L);
        if (blk < 64) {
            waitGE(ctr + CT_L, kGrid * step);
            phaseF1(p, sm);
            bumpCtr(ctr + CT_F);
        }
    }
    // final row (step kT-1)
    waitGE(ctr + CT_F, 64 * (kT - 1));
    for (int idx = blk * 256 + t; idx < kB * kV; idx += kGrid * 256) {
        int b = idx / kV, c = idx - b * kV;
        p.out[((size_t)b * kT + (kT - 1)) * kV + c] = p.lbuf[(size_t)b * kV + c] - p.lse[b];
    }
}

// ---------------- launcher ----------------

extern "C" void kernel_launch(void* const* d_in, const int* in_sizes, int n_in,
                              void* d_out, int out_size, void* d_ws, size_t ws_size,
                              hipStream_t stream) {
    const float* X    = (const float*)d_in[0];
    const float* emb  = (const float*)d_in[1];
    const float* W_ih = (const float*)d_in[2];
    const float* b_ih = (const float*)d_in[3];
    const float* W_hh = (const float*)d_in[4];
    const float* b_hh = (const float*)d_in[5];
    // d_in[6..11]: Wa, ba, Wh, bh, Wo, bo — dead (softmax over size-1 axis => weights==1)
    const float* Wlh  = (const float*)d_in[12];
    const float* blh  = (const float*)d_in[13];
    const float* Wlc  = (const float*)d_in[14];
    const float* blc  = (const float*)d_in[15];
    const float* Wout = (const float*)d_in[16];
    const float* bout = (const float*)d_in[17];
    const float* Wc0  = (const float*)d_in[18];
    const float* bc0  = (const float*)d_in[19];
    const float* Wh0  = (const float*)d_in[20];
    const float* bh0  = (const float*)d_in[21];
    float* out = (float*)d_out;

    char* cur = (char*)d_ws;
    auto carve = [&](size_t bytes) { char* p = cur; cur += (bytes + 255) & ~(size_t)255; return p; };

    u16* AbHi0 = (u16*)carve((size_t)kB * kKA * 2);
    u16* AbLo0 = (u16*)carve((size_t)kB * kKA * 2);
    u16* AbHi1 = (u16*)carve((size_t)kB * kKA * 2);
    u16* AbLo1 = (u16*)carve((size_t)kB * kKA * 2);
    float* cBJ  = (float*)carve((size_t)kB * kH * 4);
    float* gbP  = (float*)carve((size_t)kB * kG4 * 4);
    float* ctxc = (float*)carve((size_t)kB * kE * 4);
    u16* CbHi   = (u16*)carve((size_t)kB * kE * 2);
    u16* CbLo   = (u16*)carve((size_t)kB * kE * 2);
    float* XsT  = (float*)carve((size_t)kC * kB * 4);
    float* XsP  = (float*)carve((size_t)4 * kB * kC * 4);
    u16* WgHi   = (u16*)carve((size_t)kG4 * kKA * 2);
    u16* WgLo   = (u16*)carve((size_t)kG4 * kKA * 2);
    u16* WlhHi  = (u16*)carve((size_t)kE * kH * 2);
    u16* WlhLo  = (u16*)carve((size_t)kE * kH * 2);
    u16* WoHi   = (u16*)carve((size_t)10048 * kE * 2);
    u16* WoLo   = (u16*)carve((size_t)10048 * kE * 2);
    float* lbuf = (float*)carve((size_t)kB * kV * 4);
    float* lse  = (float*)carve((size_t)kB * 4);
    float* LpM  = (float*)carve((size_t)kLT * kB * 4);
    float* LpS  = (float*)carve((size_t)kLT * kB * 4);
    int*   LpI  = (int*)carve((size_t)kLT * kB * 4);
    int*   ctrs = (int*)carve(1024);

    // zero flag counters each launch (replay-safe)
    hipMemsetAsync(ctrs, 0, 1024, stream);

    // one-time setup
    k_colsum<<<512, 256, 0, stream>>>(X, XsP);
    k_colred<<<128, 256, 0, stream>>>(XsP, XsT);
    k_setupgemm<<<208, 256, 0, stream>>>(XsT, W_ih, b_ih, b_hh, Wc0, bc0,
                                         Wh0, bh0, Wlc, blc, blh,
                                         gbP, cBJ, AbHi0, AbLo0, ctxc);
    k_emb0<<<128, 256, 0, stream>>>(emb, AbHi0, AbLo0, AbHi1, AbLo1);
    k_out0<<<(kB * kV + 255) / 256, 256, 0, stream>>>(out);
    k_wgconv<<<64 * 8, 256, 0, stream>>>(W_ih, WgHi, WgLo, 0);     // k 0..511 (e)
    k_wgconv<<<64 * 16, 256, 0, stream>>>(W_hh, WgHi, WgLo, kE);   // k 512..1535 (h)
    k_wconv<<<8 * 16, 256, 0, stream>>>(Wlh, WlhHi, WlhLo, kE, kE, kH, 0, 8);
    k_wconv<<<157 * 8, 256, 0, stream>>>(Wout, WoHi, WoLo, kV, kV, kE, 0, 157);

    LoopP lp;
    lp.AbHi0 = AbHi0; lp.AbLo0 = AbLo0; lp.AbHi1 = AbHi1; lp.AbLo1 = AbLo1;
    lp.cBJ = cBJ; lp.gbP = gbP; lp.ctxc = ctxc;
    lp.CbHi = CbHi; lp.CbLo = CbLo;
    lp.WgHi = WgHi; lp.WgLo = WgLo; lp.WlhHi = WlhHi; lp.WlhLo = WlhLo;
    lp.WoHi = WoHi; lp.WoLo = WoLo;
    lp.bout = bout; lp.emb = emb;
    lp.lbuf = lbuf; lp.lse = lse; lp.LpM = LpM; lp.LpS = LpS; lp.LpI = LpI;
    lp.out = out;
    lp.ctrs = ctrs;

    k_loop<<<kGrid, 256, 0, stream>>>(lp);
}

// Round 10
// 2125.743 us; speedup vs baseline: 2.5378x; 1.5641x over previous
//
#include <hip/hip_runtime.h>
#include <math.h>

typedef unsigned short u16;
typedef __attribute__((ext_vector_type(8))) short bf16x8;
typedef __attribute__((ext_vector_type(4))) float f32x4;
typedef __attribute__((ext_vector_type(8))) unsigned short ushort8;

// Problem constants
constexpr int kB = 64;     // batch
constexpr int kN = 196;    // tokens in X
constexpr int kC = 512;    // X channels
constexpr int kE = 512;    // embedding dim
constexpr int kH = 1024;   // hidden
constexpr int kV = 10000;  // vocab (= 625*16 exactly)
constexpr int kT = 20;     // steps
constexpr int kG4 = 4 * kH;   // 4096
constexpr int kKA = 1536;     // activation K (e|h)
constexpr int kLT = 625;      // logit col-tiles of 16
constexpr int kGrid = 512;    // persistent grid (2 blocks/CU, all co-resident)

__device__ __forceinline__ float sigmoidf_(float x) { return 1.0f / (1.0f + expf(-x)); }

__device__ __forceinline__ u16 f2bf(float x) {
    unsigned u = __float_as_uint(x);
    u += 0x7FFF + ((u >> 16) & 1);
    return (u16)(u >> 16);
}
__device__ __forceinline__ float bf2f(u16 u) {
    return __uint_as_float((unsigned)u << 16);
}
__device__ __forceinline__ void splitbf(float x, u16& hi, u16& lo) {
    hi = f2bf(x);
    lo = f2bf(x - bf2f(hi));
}

// online-softmax partial merge; ties -> lower index (matches np.argmax)
__device__ __forceinline__ void mergeMS(float& M, float& S, int& I,
                                        float m2, float s2, int i2) {
    float Mn = fmaxf(M, m2);
    S = S * __expf(M - Mn) + s2 * __expf(m2 - Mn);
    if (m2 > M || (m2 == M && i2 < I)) I = i2;
    M = Mn;
}

// ---- flag-barrier primitives: SINGLE-POLLER (round-9 all-thread spin was the
// contention killer: 131k pollers on one line). Thread 0 polls; others park in
// s_barrier. One acquire fence per block covers CU L1 + XCD L2. ----
__device__ __forceinline__ void bumpCtr(int* c) {
    __syncthreads();
    if (threadIdx.x == 0) {
        __builtin_amdgcn_fence(__ATOMIC_RELEASE, "agent");
        __hip_atomic_fetch_add(c, 1, __ATOMIC_RELAXED, __HIP_MEMORY_SCOPE_AGENT);
    }
}
__device__ __forceinline__ void waitGE(const int* c, int target) {
    if (threadIdx.x == 0) {
        int it = 0;
        while (__hip_atomic_load(c, __ATOMIC_RELAXED, __HIP_MEMORY_SCOPE_AGENT) < target
               && it < (1 << 20)) {
            __builtin_amdgcn_s_sleep(8);
            ++it;
        }
        __builtin_amdgcn_fence(__ATOMIC_ACQUIRE, "agent");
    }
    __syncthreads();
}
__device__ __forceinline__ void waitGE2(const int* c1, int t1, const int* c2, int t2) {
    if (threadIdx.x == 0) {
        int it = 0;
        while ((__hip_atomic_load(c1, __ATOMIC_RELAXED, __HIP_MEMORY_SCOPE_AGENT) < t1 ||
                __hip_atomic_load(c2, __ATOMIC_RELAXED, __HIP_MEMORY_SCOPE_AGENT) < t2)
               && it < (1 << 20)) {
            __builtin_amdgcn_s_sleep(8);
            ++it;
        }
        __builtin_amdgcn_fence(__ATOMIC_ACQUIRE, "agent");
    }
    __syncthreads();
}
// counter slot offsets (separate 128B lines)
constexpr int CT_G = 0, CT_C = 32, CT_L = 64, CT_F = 96, CT_O = 128;

// ---------------- setup kernels (run once) ----------------

__global__ __launch_bounds__(256) void k_colsum(const float* __restrict__ X,
                                                float* __restrict__ XsP) {
    int gid = blockIdx.x * 256 + threadIdx.x;    // 4*64*512
    int c = gid & 511, b = (gid >> 9) & 63, ch = gid >> 15;
    const float* p = X + (size_t)b * kN * kC + (size_t)(ch * 49) * kC + c;
    float s = 0.f;
    for (int n = 0; n < 49; ++n) s += p[(size_t)n * kC];
    XsP[gid] = s;
}

__global__ __launch_bounds__(256) void k_colred(const float* __restrict__ XsP,
                                                float* __restrict__ XsT) {
    int gid = blockIdx.x * 256 + threadIdx.x;    // 64*512
    int b = gid >> 9, c = gid & 511;
    float s = 0.f;
#pragma unroll
    for (int ch = 0; ch < 4; ++ch) s += XsP[ch * 32768 + b * 512 + c];
    XsT[c * kB + b] = s;
}

// Unified fp32 setup GEMM from XsT (K=512).
__global__ __launch_bounds__(256) void k_setupgemm(const float* __restrict__ XsT,
                                                   const float* __restrict__ W_ih,
                                                   const float* __restrict__ b_ih,
                                                   const float* __restrict__ b_hh,
                                                   const float* __restrict__ Wc0,
                                                   const float* __restrict__ bc0,
                                                   const float* __restrict__ Wh0,
                                                   const float* __restrict__ bh0,
                                                   const float* __restrict__ Wlc,
                                                   const float* __restrict__ blc,
                                                   const float* __restrict__ blh,
                                                   float* __restrict__ gbP,
                                                   float* __restrict__ cBJ,
                                                   u16* __restrict__ Ab0Hi,
                                                   u16* __restrict__ Ab0Lo,
                                                   float* __restrict__ ctxc) {
    __shared__ float4 wt4[64][8];
    int t = threadIdx.x;
    int b = t & 63, q = t >> 6;
    int tile = blockIdx.x;

    const float* W; const float* bias; float scale; int ldw; int mode; int j;
    if (tile < 128) {
        j = tile * 32; W = W_ih + (size_t)kE * kG4 + j; ldw = kG4;
        bias = nullptr; scale = 1.f; mode = 0;
    } else if (tile < 160) {
        j = (tile - 128) * 32; W = Wc0 + j; ldw = kH;
        bias = bc0 + j; scale = 1.0f / 196.0f; mode = 1;
    } else if (tile < 192) {
        j = (tile - 160) * 32; W = Wh0 + j; ldw = kH;
        bias = bh0 + j; scale = 1.0f / 196.0f; mode = 2;
    } else {
        j = (tile - 192) * 32; W = Wlc + j; ldw = kE;
        bias = blc + j; scale = 1.f; mode = 3;
    }

    int lr = t >> 2, lq2 = (t & 3) * 2;
    float acc[8];
#pragma unroll
    for (int i = 0; i < 8; ++i) acc[i] = 0.f;

    for (int kt = 0; kt < kC; kt += 64) {
        const float* wrow = W + (size_t)(kt + lr) * ldw;
        float4 w0 = *reinterpret_cast<const float4*>(wrow + lq2 * 4);
        float4 w1 = *reinterpret_cast<const float4*>(wrow + lq2 * 4 + 4);
        __syncthreads();
        wt4[lr][lq2] = w0; wt4[lr][lq2 + 1] = w1;
        __syncthreads();
        const float* ap = XsT + (size_t)kt * kB + b;
#pragma unroll 8
        for (int kk = 0; kk < 64; ++kk) {
            float a = ap[kk * 64] * scale;
            float4 u0 = wt4[kk][q * 2];
            float4 u1 = wt4[kk][q * 2 + 1];
            acc[0] += a * u0.x; acc[1] += a * u0.y; acc[2] += a * u0.z; acc[3] += a * u0.w;
            acc[4] += a * u1.x; acc[5] += a * u1.y; acc[6] += a * u1.z; acc[7] += a * u1.w;
        }
    }
#pragma unroll
    for (int cc = 0; cc < 8; ++cc) {
        int col = q * 8 + cc;
        float v = acc[cc];
        if (mode == 0) {
            int jsrc = j + col;
            v += b_ih[jsrc] + b_hh[jsrc];
            int nd = ((jsrc & 1023) << 2) | (jsrc >> 10);   // gate-interleave perm
            gbP[(size_t)b * kG4 + nd] = v;
        } else if (mode == 1) {
            v = tanhf(v + bias[col]);
            cBJ[(size_t)b * kH + j + col] = v;
        } else if (mode == 2) {
            v = tanhf(v + bias[col]);
            u16 hi, lo; splitbf(v, hi, lo);
            Ab0Hi[(size_t)b * kKA + kE + j + col] = hi;
            Ab0Lo[(size_t)b * kKA + kE + j + col] = lo;
        } else {
            v += bias[col] + blh[j + col];
            ctxc[(size_t)b * kE + j + col] = v;
        }
    }
}

// transpose + bf16 hi/lo split: dst[n][k] from src[k][n]  (generic)
__global__ __launch_bounds__(256) void k_wconv(const float* __restrict__ src,
                                               u16* __restrict__ dhi,
                                               u16* __restrict__ dlo,
                                               int ld, int n_valid, int pitch,
                                               int k_off, int nxTiles) {
    __shared__ float lds[64][65];
    int t = threadIdx.x;
    int nx = blockIdx.x % nxTiles, ky = blockIdx.x / nxTiles;
    int n0 = nx * 64, k0 = ky * 64;
    int c = t & 63, r0 = t >> 6;
#pragma unroll
    for (int i = 0; i < 16; ++i) {
        int r = r0 + i * 4;
        float v = (n0 + c < n_valid) ? src[(size_t)(k0 + r) * ld + n0 + c] : 0.f;
        lds[r][c] = v;
    }
    __syncthreads();
    int nl = t >> 2, kq = t & 3;
#pragma unroll
    for (int half = 0; half < 2; ++half) {
        ushort8 vh, vl;
#pragma unroll
        for (int jj = 0; jj < 8; ++jj) {
            u16 hi, lo; splitbf(lds[kq * 16 + half * 8 + jj][nl], hi, lo);
            vh[jj] = hi; vl[jj] = lo;
        }
        size_t o = (size_t)(n0 + nl) * pitch + k_off + k0 + kq * 16 + half * 8;
        *(ushort8*)(&dhi[o]) = vh;
        *(ushort8*)(&dlo[o]) = vl;
    }
}

// gate-interleaved transpose+split for Wg: dst col n = 4*j' + gate
__global__ __launch_bounds__(256) void k_wgconv(const float* __restrict__ src,
                                                u16* __restrict__ dhi,
                                                u16* __restrict__ dlo,
                                                int k_off) {
    __shared__ float lds[64][65];
    int t = threadIdx.x;
    int nx = blockIdx.x & 63, ky = blockIdx.x >> 6;
    int n0 = nx * 64, k0 = ky * 64;
    int c = t & 63, r0 = t >> 6;
#pragma unroll
    for (int i = 0; i < 16; ++i) {
        int r = r0 + i * 4;
        int nd = n0 + c;
        int nsrc = (nd & 3) * 1024 + (nd >> 2);
        lds[r][c] = src[(size_t)(k0 + r) * kG4 + nsrc];
    }
    __syncthreads();
    int nl = t >> 2, kq = t & 3;
#pragma unroll
    for (int half = 0; half < 2; ++half) {
        ushort8 vh, vl;
#pragma unroll
        for (int jj = 0; jj < 8; ++jj) {
            u16 hi, lo; splitbf(lds[kq * 16 + half * 8 + jj][nl], hi, lo);
            vh[jj] = hi; vl[jj] = lo;
        }
        size_t o = (size_t)(n0 + nl) * kKA + k_off + k0 + kq * 16 + half * 8;
        *(ushort8*)(&dhi[o]) = vh;
        *(ushort8*)(&dlo[o]) = vl;
    }
}

// e-slot init: emb[START_IDX=1] into BOTH Ab buffers
__global__ __launch_bounds__(256) void k_emb0(const float* __restrict__ emb,
                                              u16* __restrict__ h0, u16* __restrict__ l0,
                                              u16* __restrict__ h1, u16* __restrict__ l1) {
    int gid = blockIdx.x * 256 + threadIdx.x;      // 64*512
    int b = gid >> 9, k = gid & 511;
    u16 hi, lo; splitbf(emb[kE + k], hi, lo);
    size_t o = (size_t)b * kKA + k;
    h0[o] = hi; l0[o] = lo; h1[o] = hi; l1[o] = lo;
}

__global__ __launch_bounds__(256) void k_out0(float* __restrict__ out) {
    int gid = blockIdx.x * 256 + threadIdx.x;      // 64*10000
    if (gid >= kB * kV) return;
    int b = gid / kV, v = gid - b * kV;
    out[(size_t)b * kT * kV + v] = (v == 1) ? 1.0f : 0.0f;
}

// ---------------- persistent loop kernel ----------------

struct LoopP {
    u16 *AbHi0, *AbLo0, *AbHi1, *AbLo1;
    float *cBJ, *gbP, *ctxc;
    u16 *CbHi, *CbLo;
    const u16 *WgHi, *WgLo, *WlhHi, *WlhLo, *WoHi, *WoLo;
    const float *bout, *emb;
    float *lbuf, *lse, *LpM, *LpS;
    int *LpI;
    float *out;
    int *ctrs;
};

struct SharedT {
    float sred[4][64][17];
    float redM[256];
    float redS[256];
    int   redI[256];
};

// Phase G: gates GEMM (K=1536, wave-split-K) + LSTM. Blocks [0,256).
__device__ __forceinline__ void phaseG(const LoopP& p, int step, SharedT& sm) {
    const int blk = blockIdx.x, t = threadIdx.x;
    const int l = t & 63, w = t >> 6, la = l & 15, lg = l >> 4;
    const int Pb = (step - 1) & 1, Qb = step & 1;
    const u16* aHi = Pb ? p.AbHi1 : p.AbHi0;
    const u16* aLo = Pb ? p.AbLo1 : p.AbLo0;
    u16* nHi = Qb ? p.AbHi1 : p.AbHi0;
    u16* nLo = Qb ? p.AbLo1 : p.AbLo0;
    const int n0 = blk * 16;
    const int kb = w * 384 + lg * 8;
    const u16* wh = p.WgHi + (size_t)(n0 + la) * kKA + kb;
    const u16* wl = p.WgLo + (size_t)(n0 + la) * kKA + kb;
    const u16* a0h = aHi + (size_t)la * kKA + kb;
    const u16* a0l = aLo + (size_t)la * kKA + kb;

    f32x4 acc[4];
#pragma unroll
    for (int m = 0; m < 4; ++m) acc[m] = (f32x4){0.f, 0.f, 0.f, 0.f};
    for (int ks = 0; ks < 12; ++ks) {
        int ko = ks * 32;
        bf16x8 bhi = *(const bf16x8*)(wh + ko);
        bf16x8 blo = *(const bf16x8*)(wl + ko);
#pragma unroll
        for (int m = 0; m < 4; ++m) {
            bf16x8 ahi8 = *(const bf16x8*)(a0h + (size_t)m * 16 * kKA + ko);
            bf16x8 alo8 = *(const bf16x8*)(a0l + (size_t)m * 16 * kKA + ko);
            acc[m] = __builtin_amdgcn_mfma_f32_16x16x32_bf16(ahi8, bhi, acc[m], 0, 0, 0);
            acc[m] = __builtin_amdgcn_mfma_f32_16x16x32_bf16(ahi8, blo, acc[m], 0, 0, 0);
            acc[m] = __builtin_amdgcn_mfma_f32_16x16x32_bf16(alo8, bhi, acc[m], 0, 0, 0);
        }
    }
#pragma unroll
    for (int m = 0; m < 4; ++m)
#pragma unroll
        for (int r = 0; r < 4; ++r)
            sm.sred[w][m * 16 + lg * 4 + r][la] = acc[m][r];
    __syncthreads();
    int b = l, jl = w;
    float g[4];
#pragma unroll
    for (int gi = 0; gi < 4; ++gi) {
        int cc = jl * 4 + gi;
        g[gi] = sm.sred[0][b][cc] + sm.sred[1][b][cc] + sm.sred[2][b][cc] + sm.sred[3][b][cc]
              + p.gbP[(size_t)b * kG4 + n0 + cc];
    }
    int jp = blk * 4 + jl;
    float cold = p.cBJ[b * kH + jp];
    float c2 = sigmoidf_(g[1]) * cold + sigmoidf_(g[0]) * tanhf(g[2]);
    float h2 = sigmoidf_(g[3]) * tanhf(c2);
    p.cBJ[b * kH + jp] = c2;
    u16 hh, hl; splitbf(h2, hh, hl);
    nHi[(size_t)b * kKA + kE + jp] = hh;
    nLo[(size_t)b * kKA + kE + jp] = hl;
}

// Phase C: comb GEMM. Blocks [0,32).
__device__ __forceinline__ void phaseC(const LoopP& p, int step, SharedT& sm) {
    const int blk = blockIdx.x, t = threadIdx.x;
    const int Qb = step & 1;
    const u16* aHi = Qb ? p.AbHi1 : p.AbHi0;
    const u16* aLo = Qb ? p.AbLo1 : p.AbLo0;
    const int l = t & 63, w = t >> 6, la = l & 15, lg = l >> 4;
    const int n0 = blk * 16;
    const int kb = w * 256 + lg * 8;
    const u16* wh = p.WlhHi + (size_t)(n0 + la) * kH + kb;
    const u16* wl = p.WlhLo + (size_t)(n0 + la) * kH + kb;
    const u16* a0h = aHi + (size_t)la * kKA + kE + kb;
    const u16* a0l = aLo + (size_t)la * kKA + kE + kb;
    f32x4 acc[4];
#pragma unroll
    for (int m = 0; m < 4; ++m) acc[m] = (f32x4){0.f, 0.f, 0.f, 0.f};
    for (int ks = 0; ks < 8; ++ks) {
        int ko = ks * 32;
        bf16x8 bhi = *(const bf16x8*)(wh + ko);
        bf16x8 blo = *(const bf16x8*)(wl + ko);
#pragma unroll
        for (int m = 0; m < 4; ++m) {
            bf16x8 ahi8 = *(const bf16x8*)(a0h + (size_t)m * 16 * kKA + ko);
            bf16x8 alo8 = *(const bf16x8*)(a0l + (size_t)m * 16 * kKA + ko);
            acc[m] = __builtin_amdgcn_mfma_f32_16x16x32_bf16(ahi8, bhi, acc[m], 0, 0, 0);
            acc[m] = __builtin_amdgcn_mfma_f32_16x16x32_bf16(ahi8, blo, acc[m], 0, 0, 0);
            acc[m] = __builtin_amdgcn_mfma_f32_16x16x32_bf16(alo8, bhi, acc[m], 0, 0, 0);
        }
    }
#pragma unroll
    for (int m = 0; m < 4; ++m)
#pragma unroll
        for (int r = 0; r < 4; ++r)
            sm.sred[w][m * 16 + lg * 4 + r][la] = acc[m][r];
    __syncthreads();
    int b = l, cq = w;
#pragma unroll
    for (int i = 0; i < 4; ++i) {
        int cc = cq * 4 + i;
        int col = n0 + cc;
        float v = sm.sred[0][b][cc] + sm.sred[1][b][cc] + sm.sred[2][b][cc] + sm.sred[3][b][cc];
        v += bf2f(aHi[(size_t)b * kKA + col]) + bf2f(aLo[(size_t)b * kKA + col]);
        v += p.ctxc[(size_t)b * kE + col];
        u16 hh, hl; splitbf(v, hh, hl);
        p.CbHi[(size_t)b * kE + col] = hh;
        p.CbLo[(size_t)b * kE + col] = hl;
    }
}

// Phase L: logits GEMM + online (max,sumexp,argmax) partials; grid-strided tiles.
__device__ __forceinline__ void phaseL(const LoopP& p, SharedT& sm) {
    const int t = threadIdx.x;
    const int l = t & 63, w = t >> 6, la = l & 15, lg = l >> 4;
    for (int tile = blockIdx.x; tile < kLT; tile += kGrid) {
        __syncthreads();
        const int c0 = tile * 16;
        const int kb = w * 128 + lg * 8;
        const u16* wh = p.WoHi + (size_t)(c0 + la) * kE + kb;
        const u16* wl = p.WoLo + (size_t)(c0 + la) * kE + kb;
        const u16* a0h = p.CbHi + (size_t)la * kE + kb;
        const u16* a0l = p.CbLo + (size_t)la * kE + kb;
        f32x4 acc[4];
#pragma unroll
        for (int m = 0; m < 4; ++m) acc[m] = (f32x4){0.f, 0.f, 0.f, 0.f};
#pragma unroll
        for (int ks = 0; ks < 4; ++ks) {
            int ko = ks * 32;
            bf16x8 bhi = *(const bf16x8*)(wh + ko);
            bf16x8 blo = *(const bf16x8*)(wl + ko);
#pragma unroll
            for (int m = 0; m < 4; ++m) {
                bf16x8 ahi8 = *(const bf16x8*)(a0h + (size_t)m * 16 * kE + ko);
                bf16x8 alo8 = *(const bf16x8*)(a0l + (size_t)m * 16 * kE + ko);
                acc[m] = __builtin_amdgcn_mfma_f32_16x16x32_bf16(ahi8, bhi, acc[m], 0, 0, 0);
                acc[m] = __builtin_amdgcn_mfma_f32_16x16x32_bf16(ahi8, blo, acc[m], 0, 0, 0);
                acc[m] = __builtin_amdgcn_mfma_f32_16x16x32_bf16(alo8, bhi, acc[m], 0, 0, 0);
            }
        }
#pragma unroll
        for (int m = 0; m < 4; ++m)
#pragma unroll
            for (int r = 0; r < 4; ++r)
                sm.sred[w][m * 16 + lg * 4 + r][la] = acc[m][r];
        __syncthreads();
        int b = l, cq = w;
        float vals[4];
#pragma unroll
        for (int i = 0; i < 4; ++i) {
            int cc = cq * 4 + i;
            vals[i] = sm.sred[0][b][cc] + sm.sred[1][b][cc] + sm.sred[2][b][cc] + sm.sred[3][b][cc]
                    + p.bout[c0 + cc];
        }
        *(float4*)(p.lbuf + (size_t)b * kV + c0 + cq * 4) =
            make_float4(vals[0], vals[1], vals[2], vals[3]);
        float m = vals[0]; int mi = 0;
#pragma unroll
        for (int i = 1; i < 4; ++i) if (vals[i] > m) { m = vals[i]; mi = i; }
        float se = 0.f;
#pragma unroll
        for (int i = 0; i < 4; ++i) se += __expf(vals[i] - m);
        sm.redM[t] = m; sm.redS[t] = se; sm.redI[t] = c0 + cq * 4 + mi;
        __syncthreads();
        if (t < 64) {
            float M = sm.redM[t], S = sm.redS[t]; int I = sm.redI[t];
#pragma unroll
            for (int q2 = 1; q2 < 4; ++q2)
                mergeMS(M, S, I, sm.redM[t + q2 * 64], sm.redS[t + q2 * 64], sm.redI[t + q2 * 64]);
            p.LpM[tile * 64 + t] = M; p.LpS[tile * 64 + t] = S; p.LpI[tile * 64 + t] = I;
        }
    }
}

// Phase F1: merge partials -> lse, token; gather next e into BOTH Ab buffers. Blocks [0,64).
__device__ __forceinline__ void phaseF1(const LoopP& p, SharedT& sm) {
    const int blk = blockIdx.x, t = threadIdx.x;
    int b = blk;
    float M = -3.4e38f, S = 0.f; int I = 0;
    for (int j = t; j < kLT; j += 256)
        mergeMS(M, S, I, p.LpM[j * 64 + b], p.LpS[j * 64 + b], p.LpI[j * 64 + b]);
    sm.redM[t] = M; sm.redS[t] = S; sm.redI[t] = I;
    __syncthreads();
    for (int s2 = 128; s2 > 0; s2 >>= 1) {
        if (t < s2) {
            float M1 = sm.redM[t], S1 = sm.redS[t]; int I1 = sm.redI[t];
            mergeMS(M1, S1, I1, sm.redM[t + s2], sm.redS[t + s2], sm.redI[t + s2]);
            sm.redM[t] = M1; sm.redS[t] = S1; sm.redI[t] = I1;
        }
        __syncthreads();
    }
    if (t == 0) p.lse[b] = sm.redM[0] + logf(sm.redS[0]);
    int tok = sm.redI[0];
    for (int k2 = t; k2 < kE; k2 += 256) {
        u16 hh, hl; splitbf(p.emb[(size_t)tok * kE + k2], hh, hl);
        size_t o = (size_t)b * kKA + k2;
        p.AbHi0[o] = hh; p.AbLo0[o] = hl;
        p.AbHi1[o] = hh; p.AbLo1[o] = hl;
    }
}

__global__ __launch_bounds__(256, 2) void k_loop(LoopP p) {
    __shared__ SharedT sm;
    const int blk = blockIdx.x, t = threadIdx.x;
    int* ctr = p.ctrs;

    for (int step = 1; step < kT; ++step) {
        if (blk < 256) {
            // G: wait for F1 of previous step (e-part of both Ab buffers final)
            waitGE(ctr + CT_F, 64 * (step - 1));
            phaseG(p, step, sm);
            bumpCtr(ctr + CT_G);
            if (blk < 32) {
                waitGE(ctr + CT_G, 256 * step);
                phaseC(p, step, sm);
                bumpCtr(ctr + CT_C);
            }
        } else {
            // OW: write out row step-1 (needs lbuf/lse of step-1, final after F1[step-1])
            if (step > 1) {
                waitGE(ctr + CT_F, 64 * (step - 1));
                for (int idx = (blk - 256) * 256 + t; idx < kB * kV; idx += 256 * 256) {
                    int b = idx / kV, c = idx - b * kV;
                    p.out[((size_t)b * kT + (step - 1)) * kV + c] =
                        p.lbuf[(size_t)b * kV + c] - p.lse[b];
                }
                bumpCtr(ctr + CT_O);
            }
        }
        // L: needs Cb of this step AND all out-writes of row step-1 done (lbuf overwrite)
        waitGE2(ctr + CT_C, 32 * step, ctr + CT_O, 256 * (step - 1));
        phaseL(p, sm);
        bumpCtr(ctr + CT_L);
        if (blk < 64) {
            waitGE(ctr + CT_L, kGrid * step);
            phaseF1(p, sm);
            bumpCtr(ctr + CT_F);
        }
    }
    // final row (step kT-1)
    waitGE(ctr + CT_F, 64 * (kT - 1));
    for (int idx = blk * 256 + t; idx < kB * kV; idx += kGrid * 256) {
        int b = idx / kV, c = idx - b * kV;
        p.out[((size_t)b * kT + (kT - 1)) * kV + c] = p.lbuf[(size_t)b * kV + c] - p.lse[b];
    }
}

// ---------------- launcher ----------------

extern "C" void kernel_launch(void* const* d_in, const int* in_sizes, int n_in,
                              void* d_out, int out_size, void* d_ws, size_t ws_size,
                              hipStream_t stream) {
    const float* X    = (const float*)d_in[0];
    const float* emb  = (const float*)d_in[1];
    const float* W_ih = (const float*)d_in[2];
    const float* b_ih = (const float*)d_in[3];
    const float* W_hh = (const float*)d_in[4];
    const float* b_hh = (const float*)d_in[5];
    // d_in[6..11]: Wa, ba, Wh, bh, Wo, bo — dead (softmax over size-1 axis => weights==1)
    const float* Wlh  = (const float*)d_in[12];
    const float* blh  = (const float*)d_in[13];
    const float* Wlc  = (const float*)d_in[14];
    const float* blc  = (const float*)d_in[15];
    const float* Wout = (const float*)d_in[16];
    const float* bout = (const float*)d_in[17];
    const float* Wc0  = (const float*)d_in[18];
    const float* bc0  = (const float*)d_in[19];
    const float* Wh0  = (const float*)d_in[20];
    const float* bh0  = (const float*)d_in[21];
    float* out = (float*)d_out;

    char* cur = (char*)d_ws;
    auto carve = [&](size_t bytes) { char* p = cur; cur += (bytes + 255) & ~(size_t)255; return p; };

    u16* AbHi0 = (u16*)carve((size_t)kB * kKA * 2);
    u16* AbLo0 = (u16*)carve((size_t)kB * kKA * 2);
    u16* AbHi1 = (u16*)carve((size_t)kB * kKA * 2);
    u16* AbLo1 = (u16*)carve((size_t)kB * kKA * 2);
    float* cBJ  = (float*)carve((size_t)kB * kH * 4);
    float* gbP  = (float*)carve((size_t)kB * kG4 * 4);
    float* ctxc = (float*)carve((size_t)kB * kE * 4);
    u16* CbHi   = (u16*)carve((size_t)kB * kE * 2);
    u16* CbLo   = (u16*)carve((size_t)kB * kE * 2);
    float* XsT  = (float*)carve((size_t)kC * kB * 4);
    float* XsP  = (float*)carve((size_t)4 * kB * kC * 4);
    u16* WgHi   = (u16*)carve((size_t)kG4 * kKA * 2);
    u16* WgLo   = (u16*)carve((size_t)kG4 * kKA * 2);
    u16* WlhHi  = (u16*)carve((size_t)kE * kH * 2);
    u16* WlhLo  = (u16*)carve((size_t)kE * kH * 2);
    u16* WoHi   = (u16*)carve((size_t)10048 * kE * 2);
    u16* WoLo   = (u16*)carve((size_t)10048 * kE * 2);
    float* lbuf = (float*)carve((size_t)kB * kV * 4);
    float* lse  = (float*)carve((size_t)kB * 4);
    float* LpM  = (float*)carve((size_t)kLT * kB * 4);
    float* LpS  = (float*)carve((size_t)kLT * kB * 4);
    int*   LpI  = (int*)carve((size_t)kLT * kB * 4);
    int*   ctrs = (int*)carve(1024);

    // zero flag counters each launch (replay-safe)
    hipMemsetAsync(ctrs, 0, 1024, stream);

    // one-time setup
    k_colsum<<<512, 256, 0, stream>>>(X, XsP);
    k_colred<<<128, 256, 0, stream>>>(XsP, XsT);
    k_setupgemm<<<208, 256, 0, stream>>>(XsT, W_ih, b_ih, b_hh, Wc0, bc0,
                                         Wh0, bh0, Wlc, blc, blh,
                                         gbP, cBJ, AbHi0, AbLo0, ctxc);
    k_emb0<<<128, 256, 0, stream>>>(emb, AbHi0, AbLo0, AbHi1, AbLo1);
    k_out0<<<(kB * kV + 255) / 256, 256, 0, stream>>>(out);
    k_wgconv<<<64 * 8, 256, 0, stream>>>(W_ih, WgHi, WgLo, 0);     // k 0..511 (e)
    k_wgconv<<<64 * 16, 256, 0, stream>>>(W_hh, WgHi, WgLo, kE);   // k 512..1535 (h)
    k_wconv<<<8 * 16, 256, 0, stream>>>(Wlh, WlhHi, WlhLo, kE, kE, kH, 0, 8);
    k_wconv<<<157 * 8, 256, 0, stream>>>(Wout, WoHi, WoLo, kV, kV, kE, 0, 157);

    LoopP lp;
    lp.AbHi0 = AbHi0; lp.AbLo0 = AbLo0; lp.AbHi1 = AbHi1; lp.AbLo1 = AbLo1;
    lp.cBJ = cBJ; lp.gbP = gbP; lp.ctxc = ctxc;
    lp.CbHi = CbHi; lp.CbLo = CbLo;
    lp.WgHi = WgHi; lp.WgLo = WgLo; lp.WlhHi = WlhHi; lp.WlhLo = WlhLo;
    lp.WoHi = WoHi; lp.WoLo = WoLo;
    lp.bout = bout; lp.emb = emb;
    lp.lbuf = lbuf; lp.lse = lse; lp.LpM = LpM; lp.LpS = LpS; lp.LpI = LpI;
    lp.out = out;
    lp.ctrs = ctrs;

    k_loop<<<kGrid, 256, 0, stream>>>(lp);
}